// Round 3
// 477.292 us; speedup vs baseline: 1.1646x; 1.1646x over previous
//
#include <hip/hip_runtime.h>

#define T_ 1000
#define F_ 257
#define L2E 1.4426950408889634f

typedef short bf16x8 __attribute__((ext_vector_type(8)));
typedef short bf16x4 __attribute__((ext_vector_type(4)));
typedef float f32x4  __attribute__((ext_vector_type(4)));

__device__ __forceinline__ unsigned short f2bf(float f) {
    unsigned int u = __float_as_uint(f);
    u += 0x7fffu + ((u >> 16) & 1u);          // round-to-nearest-even
    return (unsigned short)(u >> 16);
}
__device__ __forceinline__ float bf2f(unsigned short h) {
    return __uint_as_float(((unsigned int)h) << 16);
}
// 2 fp32 -> packed 2x bf16 (RNE) in one instruction
__device__ __forceinline__ unsigned cvt_pk_bf16(float a, float b) {
    unsigned r;
    asm("v_cvt_pk_bf16_f32 %0, %1, %2" : "=v"(r) : "v"(a), "v"(b));
    return r;
}
// 1/(1+2^-a) : sigmoid of the log2e-prescaled logit
__device__ __forceinline__ float sig2(float a) {
    return __builtin_amdgcn_rcpf(1.0f + __builtin_amdgcn_exp2f(-a));
}

extern "C" __global__ __launch_bounds__(256, 4)
void gru_mfma(const float* __restrict__ x, const float* __restrict__ h,
              const float* __restrict__ pre_w, const float* __restrict__ pre_b,
              const float* __restrict__ xz_w, const float* __restrict__ xz_b,
              const float* __restrict__ xr_w, const float* __restrict__ xr_b,
              const float* __restrict__ xn_w, const float* __restrict__ xn_b,
              const float* __restrict__ hz_w, const float* __restrict__ hz_b,
              const float* __restrict__ hr_w, const float* __restrict__ hr_b,
              const float* __restrict__ hn_w, const float* __restrict__ hn_b,
              float* __restrict__ out)
{
    // B^T weight tables [n][k] (bf16), z/r rows pre-scaled by log2e, n rows by 2*log2e.
    __shared__ __align__(16) unsigned short BZX[16][160]; // n<8: xz|hz ; n>=8: xn|0
    __shared__ __align__(16) unsigned short BR [ 8][160]; // xr|hr (c>=8 lanes read duplicates; epilogue guarded)
    __shared__ __align__(16) unsigned short BHN[ 8][ 96]; // hn taps<10 (zero-masked in regs for c<8)
    __shared__ __align__(16) unsigned short BPR[ 8][ 64]; // pre (k=tap*4+ci, taps<10)
    // channel-last bf16 activation tiles. sh/sxp/srh share a 48-col (768 B) row stride so
    // all phase-3/4 tap addresses are {per-lane const} + {row*768 + fs*256}.
    // One extra row on sx/sh/sxp gives wrap-slack so junk-pixel reads need no imin clamp.
    __shared__ __align__(16) unsigned short sx [12][44][4];
    __shared__ __align__(16) unsigned short sh [11][48][8];
    __shared__ __align__(16) unsigned short sxp[11][48][8];
    __shared__ __align__(16) unsigned short srh[ 9][48][8];

    const int tid  = threadIdx.x;
    const int lane = tid & 63;
    const int wave = tid >> 6;
    const int am   = lane & 15;  // A-fragment row (pixel within 16-seg)
    const int q    = lane >> 4;  // quad
    const int c    = am;         // C/D column (output channel) in epilogues
    const int c7   = c & 7;
    const int f0   = blockIdx.x * 32;
    const int t0   = blockIdx.y * 8;
    const int b    = blockIdx.z;

    // ---- zero only table regions not fully overwritten by the fill ----
    {
        uint4 z4 = {0u, 0u, 0u, 0u};
        for (int i = tid; i < 320; i += 256) ((uint4*)BZX)[i] = z4;
        if (tid < 96) ((uint4*)BHN)[tid] = z4;
        if (tid < 64) ((uint4*)BPR)[tid] = z4;
    }
    __syncthreads();

    // ---- fill weight tables (global OIHW -> [n][k]), activation scales folded in ----
    for (int i = tid; i < 640; i += 256) {
        int co  = i / 80;
        int rem = i - co * 80;
        int ci  = rem / 10;
        int tf  = rem - ci * 10;           // kt*5+kf
        int k   = tf * 8 + ci;
        BZX[co][k]      = f2bf(xz_w[i] * L2E);
        BZX[8+co][k]    = f2bf(xn_w[i] * (2.0f * L2E));
        BZX[co][80+k]   = f2bf(hz_w[i] * L2E);
        BR [co][k]      = f2bf(xr_w[i] * L2E);
        BR [co][80+k]   = f2bf(hr_w[i] * L2E);
        BHN[co][k]      = f2bf(hn_w[i] * (2.0f * L2E));
    }
    for (int i = tid; i < 320; i += 256) {
        int co  = i / 40;
        int rem = i - co * 40;
        int ci  = rem / 10;
        int tf  = rem - ci * 10;
        BPR[co][tf*4 + ci] = f2bf(pre_w[i]);   // elu input: unscaled
    }

    // ---- stage x (rows gt=t0-3+r, cols gf=f0-6+col, zero OOR) ----
    for (int i = tid; i < 11*44; i += 256) {
        int r = i / 44, col = i - r*44;
        int gt = t0 - 3 + r, gf = f0 - 6 + col;
        uint2 pk = {0u, 0u};
        if (gt >= 0 && (unsigned)gf < 257u) {
            const float* p = x + ((size_t)(b * 4) * T_ + gt) * F_ + gf;
            pk.x = cvt_pk_bf16(p[0],        p[257000]);
            pk.y = cvt_pk_bf16(p[2*257000], p[3*257000]);
        }
        *(uint2*)&sx[r][col][0] = pk;
    }
    // ---- stage h (rows gt=t0-2+r, cols gf=f0-4+col) ----
    for (int i = tid; i < 10*40; i += 256) {
        int r = i / 40, col = i - r*40;
        int gt = t0 - 2 + r, gf = f0 - 4 + col;
        uint4 pk = {0u, 0u, 0u, 0u};
        if (gt >= 0 && (unsigned)gf < 257u) {
            const float* p = h + ((size_t)(b * 8) * T_ + gt) * F_ + gf;
            pk.x = cvt_pk_bf16(p[0],        p[257000]);
            pk.y = cvt_pk_bf16(p[2*257000], p[3*257000]);
            pk.z = cvt_pk_bf16(p[4*257000], p[5*257000]);
            pk.w = cvt_pk_bf16(p[6*257000], p[7*257000]);
        }
        *(uint4*)&sh[r][col][0] = pk;
    }

    // ---- per-lane accumulator biases (col = channel), pre-scaled ----
    float bias2 = pre_b[c7];
    float bias3 = (xr_b[c7] + hr_b[c7]) * L2E;
    float bias4 = (c < 8) ? (xz_b[c] + hz_b[c]) * L2E
                          : (xn_b[c7] + hn_b[c7]) * (2.0f * L2E);
    __syncthreads();

    // ================= phase 2: xp = elu(pre-conv(x)), 10 x 48 region =================
    {
        bf16x8 fpre[2];
        const unsigned short* pA[2][2];
        #pragma unroll
        for (int s = 0; s < 2; ++s) {
            fpre[s] = *(const bf16x8*)&BPR[c7][s*32 + q*8];
            int ta = 8*s + 2*q, tb = ta + 1;
            int t1 = (ta < 10) ? ta : 0;      // padded taps -> tap 0 (weights are 0)
            int t2 = (tb < 10) ? tb : 0;
            int kt1 = (t1 >= 5), kf1 = t1 - kt1*5;
            int kt2 = (t2 >= 5), kf2 = t2 - kt2*5;
            pA[s][0] = &sx[kt1][am + kf1][0];
            pA[s][1] = &sx[kt2][am + kf2][0];
        }
        for (int u = wave; u < 30; u += 4) {
            int r2 = u / 3, fs = u - r2*3;
            int disp = r2*352 + fs*128;       // sx row stride 44*8=352 B
            f32x4 acc = {bias2, bias2, bias2, bias2};
            #pragma unroll
            for (int s = 0; s < 2; ++s) {
                union { bf16x8 v; bf16x4 hh[2]; } a;
                a.hh[0] = *(const bf16x4*)((const char*)pA[s][0] + disp);
                a.hh[1] = *(const bf16x4*)((const char*)pA[s][1] + disp);
                acc = __builtin_amdgcn_mfma_f32_16x16x32_bf16(a.v, fpre[s], acc, 0, 0, 0);
            }
            int gt = t0 - 2 + r2;
            unsigned short* ps = &sxp[r2][fs*16 + q*4][c];
            if (gt >= 0) {
                int g0 = f0 - 4 + fs*16 + q*4;
                float w0 = acc[0], w1 = acc[1], w2 = acc[2], w3 = acc[3];
                float e0 = __builtin_amdgcn_exp2f(w0 * L2E) - 1.0f;
                float e1 = __builtin_amdgcn_exp2f(w1 * L2E) - 1.0f;
                float e2 = __builtin_amdgcn_exp2f(w2 * L2E) - 1.0f;
                float e3 = __builtin_amdgcn_exp2f(w3 * L2E) - 1.0f;
                w0 = (w0 > 0.0f) ? w0 : e0;
                w1 = (w1 > 0.0f) ? w1 : e1;
                w2 = (w2 > 0.0f) ? w2 : e2;
                w3 = (w3 > 0.0f) ? w3 : e3;
                w0 = ((unsigned)(g0 + 0) < 257u) ? w0 : 0.0f;
                w1 = ((unsigned)(g0 + 1) < 257u) ? w1 : 0.0f;
                w2 = ((unsigned)(g0 + 2) < 257u) ? w2 : 0.0f;
                w3 = ((unsigned)(g0 + 3) < 257u) ? w3 : 0.0f;
                unsigned pk01 = cvt_pk_bf16(w0, w1);
                unsigned pk23 = cvt_pk_bf16(w2, w3);
                if (c < 8) {
                    ps[0]  = (unsigned short)pk01;
                    ps[8]  = (unsigned short)(pk01 >> 16);
                    ps[16] = (unsigned short)pk23;
                    ps[24] = (unsigned short)(pk23 >> 16);
                }
            } else if (c < 8) {
                ps[0] = 0; ps[8] = 0; ps[16] = 0; ps[24] = 0;
            }
        }
    }
    __syncthreads();

    // ================= phase 3: rh = sigmoid(r-conv) * h, 9 x 48 region =================
    {
        bf16x8 fr[5];
        const unsigned short* p3[5];
        #pragma unroll
        for (int s = 0; s < 5; ++s) {
            fr[s] = *(const bf16x8*)&BR[c7][s*32 + q*8];
            int tap = s*4 + q;
            if (tap < 10) {
                int kt = (tap >= 5), kf = tap - kt*5;
                p3[s] = &sxp[kt][am + kf][0];
            } else {
                int tt = tap - 10;
                int kt = (tt >= 5), kf = tt - kt*5;
                p3[s] = &sh[kt][am + kf][0];
            }
        }
        for (int u = wave; u < 27; u += 4) {
            int r3 = u / 3, fs = u - r3*3;
            int disp = r3*768 + fs*256;
            f32x4 acc = {bias3, bias3, bias3, bias3};
            #pragma unroll
            for (int s = 0; s < 5; ++s) {
                bf16x8 a = *(const bf16x8*)((const char*)p3[s] + disp);
                acc = __builtin_amdgcn_mfma_f32_16x16x32_bf16(a, fr[s], acc, 0, 0, 0);
            }
            if (c < 8) {
                const unsigned short* ph = &sh[r3 + 1][2 + fs*16 + q*4][c];
                unsigned short*       ps = &srh[r3][fs*16 + q*4][c];
                float v0 = sig2(acc[0]) * bf2f(ph[0]);
                float v1 = sig2(acc[1]) * bf2f(ph[8]);
                float v2 = sig2(acc[2]) * bf2f(ph[16]);
                float v3 = sig2(acc[3]) * bf2f(ph[24]);
                unsigned pk01 = cvt_pk_bf16(v0, v1);
                unsigned pk23 = cvt_pk_bf16(v2, v3);
                ps[0]  = (unsigned short)pk01;
                ps[8]  = (unsigned short)(pk01 >> 16);
                ps[16] = (unsigned short)pk23;
                ps[24] = (unsigned short)(pk23 >> 16);
            }
        }
    }
    __syncthreads();

    // ================= phase 4: z | n, center 8 x 32, write out =================
    {
        bf16x8 fzx[5], fhn[3];
        const unsigned short* p4[5];
        const unsigned short* p4h[3];
        #pragma unroll
        for (int s = 0; s < 5; ++s) {
            fzx[s] = *(const bf16x8*)&BZX[c][s*32 + q*8];
            int tap = s*4 + q;
            if (tap < 10) {
                int kt = (tap >= 5), kf = tap - kt*5;
                p4[s] = &sxp[1 + kt][2 + am + kf][0];
            } else {
                int tt = tap - 10;
                int kt = (tt >= 5), kf = tt - kt*5;
                p4[s] = &sh[1 + kt][2 + am + kf][0];
            }
        }
        bf16x8 zz = {0, 0, 0, 0, 0, 0, 0, 0};
        #pragma unroll
        for (int s = 0; s < 3; ++s) {
            bf16x8 w = *(const bf16x8*)&BHN[c7][s*32 + q*8];
            fhn[s] = (c >= 8) ? w : zz;       // z-columns must not see srh contributions
            int tap = s*4 + q;
            int tt = (tap < 10) ? tap : 0;    // taps 10,11 have zero weights
            int kt = (tt >= 5), kf = tt - kt*5;
            p4h[s] = &srh[kt][am + kf][0];
        }
        float sgn  = (c < 8) ? 1.0f : 2.0f;   // y = sgn*sigma - (sgn-1): sigmoid | tanh
        float soff = (c < 8) ? 0.0f : -1.0f;
        float* pout = out + (size_t)(b * 8 + c7) * 257000 + t0 * 257 + f0 + q * 4;
        for (int u = wave; u < 16; u += 4) {
            int i4 = u >> 1, fs = u & 1;
            int disp = i4*768 + fs*256;
            f32x4 acc = {bias4, bias4, bias4, bias4};
            #pragma unroll
            for (int s = 0; s < 5; ++s) {
                bf16x8 a = *(const bf16x8*)((const char*)p4[s] + disp);
                acc = __builtin_amdgcn_mfma_f32_16x16x32_bf16(a, fzx[s], acc, 0, 0, 0);
            }
            #pragma unroll
            for (int s = 0; s < 3; ++s) {
                bf16x8 a = *(const bf16x8*)((const char*)p4h[s] + disp);
                acc = __builtin_amdgcn_mfma_f32_16x16x32_bf16(a, fhn[s], acc, 0, 0, 0);
            }
            float y0 = fmaf(sig2(acc[0]), sgn, soff);
            float y1 = fmaf(sig2(acc[1]), sgn, soff);
            float y2 = fmaf(sig2(acc[2]), sgn, soff);
            float y3 = fmaf(sig2(acc[3]), sgn, soff);
            float n0 = __shfl_xor(y0, 8);     // all lanes: swap z <-> n
            float n1 = __shfl_xor(y1, 8);
            float n2 = __shfl_xor(y2, 8);
            float n3 = __shfl_xor(y3, 8);
            if (c < 8) {
                const unsigned short* ph = &sh[i4 + 2][4 + fs*16 + q*4][c];
                float h0 = bf2f(ph[0]);
                float h1 = bf2f(ph[8]);
                float h2 = bf2f(ph[16]);
                float h3 = bf2f(ph[24]);
                float o0 = fmaf(y0, n0 - h0, h0);   // (1-z)h + z n
                float o1 = fmaf(y1, n1 - h1, h1);
                float o2 = fmaf(y2, n2 - h2, h2);
                float o3 = fmaf(y3, n3 - h3, h3);
                float* pp = pout + i4*257 + fs*16;
                int g0 = f0 + fs*16 + q*4;
                if (g0 + 3 < 257) {
                    pp[0] = o0; pp[1] = o1; pp[2] = o2; pp[3] = o3;
                } else {
                    if (g0     < 257) pp[0] = o0;
                    if (g0 + 1 < 257) pp[1] = o1;
                    if (g0 + 2 < 257) pp[2] = o2;
                    if (g0 + 3 < 257) pp[3] = o3;
                }
            }
        }
    }
}

extern "C" void kernel_launch(void* const* d_in, const int* in_sizes, int n_in,
                              void* d_out, int out_size, void* d_ws, size_t ws_size,
                              hipStream_t stream) {
    const float* x     = (const float*)d_in[0];
    const float* h     = (const float*)d_in[1];
    const float* pre_w = (const float*)d_in[2];
    const float* pre_b = (const float*)d_in[3];
    const float* xz_w  = (const float*)d_in[4];
    const float* xz_b  = (const float*)d_in[5];
    const float* xr_w  = (const float*)d_in[6];
    const float* xr_b  = (const float*)d_in[7];
    const float* xn_w  = (const float*)d_in[8];
    const float* xn_b  = (const float*)d_in[9];
    const float* hz_w  = (const float*)d_in[10];
    const float* hz_b  = (const float*)d_in[11];
    const float* hr_w  = (const float*)d_in[12];
    const float* hr_b  = (const float*)d_in[13];
    const float* hn_w  = (const float*)d_in[14];
    const float* hn_b  = (const float*)d_in[15];
    float* out = (float*)d_out;

    dim3 grid(9, 125, 16);   // ceil(257/32) x 1000/8 x B
    dim3 block(256);
    gru_mfma<<<grid, block, 0, stream>>>(x, h,
        pre_w, pre_b, xz_w, xz_b, xr_w, xr_b, xn_w, xn_b,
        hz_w, hz_b, hr_w, hr_b, hn_w, hn_b, out);
}

// Round 6
// 457.262 us; speedup vs baseline: 1.2156x; 1.0438x over previous
//
#include <hip/hip_runtime.h>

#define T_ 1000
#define F_ 257
#define L2E 1.4426950408889634f

typedef short bf16x8 __attribute__((ext_vector_type(8)));
typedef short bf16x4 __attribute__((ext_vector_type(4)));
typedef float f32x4  __attribute__((ext_vector_type(4)));

__device__ __forceinline__ unsigned short f2bf(float f) {
    unsigned int u = __float_as_uint(f);
    u += 0x7fffu + ((u >> 16) & 1u);          // round-to-nearest-even
    return (unsigned short)(u >> 16);
}
__device__ __forceinline__ float bf2f(unsigned short h) {
    return __uint_as_float(((unsigned int)h) << 16);
}
// 2 fp32 -> packed 2x bf16 (RNE) in one instruction
__device__ __forceinline__ unsigned cvt_pk_bf16(float a, float b) {
    unsigned r;
    asm("v_cvt_pk_bf16_f32 %0, %1, %2" : "=v"(r) : "v"(a), "v"(b));
    return r;
}
// 1/(1+2^-a) : sigmoid of the log2e-prescaled logit
__device__ __forceinline__ float sig2(float a) {
    return __builtin_amdgcn_rcpf(1.0f + __builtin_amdgcn_exp2f(-a));
}

extern "C" __global__ __launch_bounds__(256, 4)
void gru_mfma(const float* __restrict__ x, const float* __restrict__ h,
              const float* __restrict__ pre_w, const float* __restrict__ pre_b,
              const float* __restrict__ xz_w, const float* __restrict__ xz_b,
              const float* __restrict__ xr_w, const float* __restrict__ xr_b,
              const float* __restrict__ xn_w, const float* __restrict__ xn_b,
              const float* __restrict__ hz_w, const float* __restrict__ hz_b,
              const float* __restrict__ hr_w, const float* __restrict__ hr_b,
              const float* __restrict__ hn_w, const float* __restrict__ hn_b,
              float* __restrict__ out)
{
    // B^T weight tables [n][k] (bf16), z/r rows pre-scaled by log2e, n rows by 2*log2e.
    __shared__ __align__(16) unsigned short BZX[16][160]; // n<8: xz|hz ; n>=8: xn|0
    __shared__ __align__(16) unsigned short BR [ 8][160]; // xr|hr (cols 8-15 duplicate 0-7)
    __shared__ __align__(16) unsigned short BHN[ 8][ 96]; // hn taps<10 (zero-masked in regs for c<8)
    __shared__ __align__(16) unsigned short BPR[ 8][ 64]; // pre (k=tap*4+ci, taps<10)
    // channel-last bf16 activation tiles. ALL tiles now have strides making phase
    // displacements linear in u: sx row=384B (disp=u*128), sh/sxp/srh row=768B (disp=u*256).
    // Extra rows give wrap-slack; wrap/junk reads only feed provably-unused outputs.
    __shared__ __align__(16) unsigned short sx [12][48][4];  // cols 0..43 staged
    __shared__ __align__(16) unsigned short sh [11][48][8];  // cols 0..39 staged
    __shared__ __align__(16) unsigned short sxp[11][48][8];
    __shared__ __align__(16) unsigned short srh[ 9][48][8];

    const int tid  = threadIdx.x;
    const int lane = tid & 63;
    const int wave = tid >> 6;
    const int am   = lane & 15;  // A-fragment row (pixel within 16-seg)
    const int q    = lane >> 4;  // quad
    const int c    = am;         // C/D column (output channel) in epilogues
    const int c7   = c & 7;
    const bool hiB = (c >= 8);   // lane-split: c<8 handles element A, c>=8 element B
    const int f0   = blockIdx.x * 32;
    const int t0   = blockIdx.y * 8;
    const int b    = blockIdx.z;

    // ---- zero only table regions not fully overwritten by the fill ----
    {
        uint4 z4 = {0u, 0u, 0u, 0u};
        for (int i = tid; i < 320; i += 256) ((uint4*)BZX)[i] = z4;
        if (tid < 96) ((uint4*)BHN)[tid] = z4;
        if (tid < 64) ((uint4*)BPR)[tid] = z4;
    }
    __syncthreads();

    // ---- fill weight tables (global OIHW -> [n][k]), activation scales folded in ----
    for (int i = tid; i < 640; i += 256) {
        int co  = i / 80;
        int rem = i - co * 80;
        int ci  = rem / 10;
        int tf  = rem - ci * 10;           // kt*5+kf
        int k   = tf * 8 + ci;
        BZX[co][k]      = f2bf(xz_w[i] * L2E);
        BZX[8+co][k]    = f2bf(xn_w[i] * (2.0f * L2E));
        BZX[co][80+k]   = f2bf(hz_w[i] * L2E);
        BR [co][k]      = f2bf(xr_w[i] * L2E);
        BR [co][80+k]   = f2bf(hr_w[i] * L2E);
        BHN[co][k]      = f2bf(hn_w[i] * (2.0f * L2E));
    }
    for (int i = tid; i < 320; i += 256) {
        int co  = i / 40;
        int rem = i - co * 40;
        int ci  = rem / 10;
        int tf  = rem - ci * 10;
        BPR[co][tf*4 + ci] = f2bf(pre_w[i]);   // elu input: unscaled
    }

    // ---- stage x (rows gt=t0-3+r, cols gf=f0-6+col, zero OOR) ----
    for (int i = tid; i < 11*44; i += 256) {
        int r = i / 44, col = i - r*44;
        int gt = t0 - 3 + r, gf = f0 - 6 + col;
        uint2 pk = {0u, 0u};
        if (gt >= 0 && (unsigned)gf < 257u) {
            const float* p = x + ((size_t)(b * 4) * T_ + gt) * F_ + gf;
            pk.x = cvt_pk_bf16(p[0],        p[257000]);
            pk.y = cvt_pk_bf16(p[2*257000], p[3*257000]);
        }
        *(uint2*)&sx[r][col][0] = pk;
    }
    // ---- stage h (rows gt=t0-2+r, cols gf=f0-4+col) ----
    for (int i = tid; i < 10*40; i += 256) {
        int r = i / 40, col = i - r*40;
        int gt = t0 - 2 + r, gf = f0 - 4 + col;
        uint4 pk = {0u, 0u, 0u, 0u};
        if (gt >= 0 && (unsigned)gf < 257u) {
            const float* p = h + ((size_t)(b * 8) * T_ + gt) * F_ + gf;
            pk.x = cvt_pk_bf16(p[0],        p[257000]);
            pk.y = cvt_pk_bf16(p[2*257000], p[3*257000]);
            pk.z = cvt_pk_bf16(p[4*257000], p[5*257000]);
            pk.w = cvt_pk_bf16(p[6*257000], p[7*257000]);
        }
        *(uint4*)&sh[r][col][0] = pk;
    }

    // ---- per-lane accumulator biases (col = channel), pre-scaled ----
    float bias2 = pre_b[c7];
    float bias3 = (xr_b[c7] + hr_b[c7]) * L2E;
    float bias4 = (c < 8) ? (xz_b[c] + hz_b[c]) * L2E
                          : (xn_b[c7] + hn_b[c7]) * (2.0f * L2E);
    __syncthreads();

    // ================= phase 2: xp = elu(pre-conv(x)), 10 x 48 region =================
    // pair-unrolled (u, u+1); lane-split epilogue (c<8 -> A, c>=8 -> B, dup columns)
    {
        bf16x8 fpre[2];
        const unsigned short* pA[2][2];
        #pragma unroll
        for (int s = 0; s < 2; ++s) {
            fpre[s] = *(const bf16x8*)&BPR[c7][s*32 + q*8];
            int ta = 8*s + 2*q, tb = ta + 1;
            int t1 = (ta < 10) ? ta : 0;      // padded taps -> tap 0 (weights are 0)
            int t2 = (tb < 10) ? tb : 0;
            int kt1 = (t1 >= 5), kf1 = t1 - kt1*5;
            int kt2 = (t2 >= 5), kf2 = t2 - kt2*5;
            pA[s][0] = &sx[kt1][am + kf1][0];
            pA[s][1] = &sx[kt2][am + kf2][0];
        }
        unsigned short* psxp = &sxp[0][q*4][c7];
        for (int u = 2*wave; u < 30; u += 8) {
            int d0 = u << 7, d1 = d0 + 128;   // sx disp = u*128 B
            f32x4 aA = {bias2, bias2, bias2, bias2};
            f32x4 aB = {bias2, bias2, bias2, bias2};
            #pragma unroll
            for (int s = 0; s < 2; ++s) {
                union { bf16x8 v; bf16x4 hh[2]; } a0, a1;
                a0.hh[0] = *(const bf16x4*)((const char*)pA[s][0] + d0);
                a0.hh[1] = *(const bf16x4*)((const char*)pA[s][1] + d0);
                a1.hh[0] = *(const bf16x4*)((const char*)pA[s][0] + d1);
                a1.hh[1] = *(const bf16x4*)((const char*)pA[s][1] + d1);
                aA = __builtin_amdgcn_mfma_f32_16x16x32_bf16(a0.v, fpre[s], aA, 0, 0, 0);
                aB = __builtin_amdgcn_mfma_f32_16x16x32_bf16(a1.v, fpre[s], aB, 0, 0, 0);
            }
            int r2A = u / 3;
            int fsA = u - r2A*3;
            int wrap = (fsA == 2);
            int r2X = hiB ? (r2A + wrap)            : r2A;
            int fsX = hiB ? (wrap ? 0 : fsA + 1)    : fsA;
            int gtX = t0 - 2 + r2X;
            int g0X = f0 - 4 + fsX*16 + q*4;
            float w0 = hiB ? aB[0] : aA[0];
            float w1 = hiB ? aB[1] : aA[1];
            float w2 = hiB ? aB[2] : aA[2];
            float w3 = hiB ? aB[3] : aA[3];
            float e0 = __builtin_amdgcn_exp2f(w0 * L2E) - 1.0f;
            float e1 = __builtin_amdgcn_exp2f(w1 * L2E) - 1.0f;
            float e2 = __builtin_amdgcn_exp2f(w2 * L2E) - 1.0f;
            float e3 = __builtin_amdgcn_exp2f(w3 * L2E) - 1.0f;
            w0 = (w0 > 0.0f) ? w0 : e0;
            w1 = (w1 > 0.0f) ? w1 : e1;
            w2 = (w2 > 0.0f) ? w2 : e2;
            w3 = (w3 > 0.0f) ? w3 : e3;
            bool rowok = (gtX >= 0);
            w0 = (rowok && ((unsigned)(g0X + 0) < 257u)) ? w0 : 0.0f;
            w1 = (rowok && ((unsigned)(g0X + 1) < 257u)) ? w1 : 0.0f;
            w2 = (rowok && ((unsigned)(g0X + 2) < 257u)) ? w2 : 0.0f;
            w3 = (rowok && ((unsigned)(g0X + 3) < 257u)) ? w3 : 0.0f;
            unsigned pk01 = cvt_pk_bf16(w0, w1);
            unsigned pk23 = cvt_pk_bf16(w2, w3);
            unsigned short* ps = psxp + (u << 7) + (hiB ? 128 : 0);  // sxp disp = u*128 shorts
            ps[0]  = (unsigned short)pk01;
            ps[8]  = (unsigned short)(pk01 >> 16);
            ps[16] = (unsigned short)pk23;
            ps[24] = (unsigned short)(pk23 >> 16);
        }
    }
    __syncthreads();

    // ================= phase 3: rh = sigmoid(r-conv) * h, 9 x 48 region =================
    // pair-unrolled; lane-split epilogue (BR cols 8-15 duplicate 0-7)
    {
        bf16x8 fr[5];
        const unsigned short* p3[5];
        #pragma unroll
        for (int s = 0; s < 5; ++s) {
            fr[s] = *(const bf16x8*)&BR[c7][s*32 + q*8];
            int tap = s*4 + q;
            if (tap < 10) {
                int kt = (tap >= 5), kf = tap - kt*5;
                p3[s] = &sxp[kt][am + kf][0];
            } else {
                int tt = tap - 10;
                int kt = (tt >= 5), kf = tt - kt*5;
                p3[s] = &sh[kt][am + kf][0];
            }
        }
        const unsigned short* ph3 = &sh[1][2 + q*4][c7];
        unsigned short*       ps3 = &srh[0][q*4][c7];
        for (int u = 2*wave; u < 27; u += 8) {
            int d0 = u << 8, d1 = d0 + 256;   // disp = u*256 B
            f32x4 aA = {bias3, bias3, bias3, bias3};
            f32x4 aB = {bias3, bias3, bias3, bias3};
            #pragma unroll
            for (int s = 0; s < 5; ++s) {
                bf16x8 a0 = *(const bf16x8*)((const char*)p3[s] + d0);
                bf16x8 a1 = *(const bf16x8*)((const char*)p3[s] + d1);
                aA = __builtin_amdgcn_mfma_f32_16x16x32_bf16(a0, fr[s], aA, 0, 0, 0);
                aB = __builtin_amdgcn_mfma_f32_16x16x32_bf16(a1, fr[s], aB, 0, 0, 0);
            }
            int off = (u << 7) + (hiB ? 128 : 0);   // u*128 shorts (+1 element for B)
            const unsigned short* ph = ph3 + off;
            unsigned short*       ps = ps3 + off;
            float s0 = hiB ? aB[0] : aA[0];
            float s1 = hiB ? aB[1] : aA[1];
            float s2 = hiB ? aB[2] : aA[2];
            float s3 = hiB ? aB[3] : aA[3];
            float v0 = sig2(s0) * bf2f(ph[0]);
            float v1 = sig2(s1) * bf2f(ph[8]);
            float v2 = sig2(s2) * bf2f(ph[16]);
            float v3 = sig2(s3) * bf2f(ph[24]);
            unsigned pk01 = cvt_pk_bf16(v0, v1);
            unsigned pk23 = cvt_pk_bf16(v2, v3);
            if (!hiB || (u + 1 < 27)) {
                ps[0]  = (unsigned short)pk01;
                ps[8]  = (unsigned short)(pk01 >> 16);
                ps[16] = (unsigned short)pk23;
                ps[24] = (unsigned short)(pk23 >> 16);
            }
        }
    }
    __syncthreads();

    // ================= phase 4: z | n, center 8 x 32, write out =================
    // pair-unrolled: pair = (i4, fs=0) and (i4, fs=1)
    {
        bf16x8 fzx[5], fhn[3];
        const unsigned short* p4[5];
        const unsigned short* p4h[3];
        #pragma unroll
        for (int s = 0; s < 5; ++s) {
            fzx[s] = *(const bf16x8*)&BZX[c][s*32 + q*8];
            int tap = s*4 + q;
            if (tap < 10) {
                int kt = (tap >= 5), kf = tap - kt*5;
                p4[s] = &sxp[1 + kt][2 + am + kf][0];
            } else {
                int tt = tap - 10;
                int kt = (tt >= 5), kf = tt - kt*5;
                p4[s] = &sh[1 + kt][2 + am + kf][0];
            }
        }
        bf16x8 zz = {0, 0, 0, 0, 0, 0, 0, 0};
        #pragma unroll
        for (int s = 0; s < 3; ++s) {
            bf16x8 w = *(const bf16x8*)&BHN[c7][s*32 + q*8];
            fhn[s] = (c >= 8) ? w : zz;       // z-columns must not see srh contributions
            int tap = s*4 + q;
            int tt = (tap < 10) ? tap : 0;    // taps 10,11 have zero weights
            int kt = (tt >= 5), kf = tt - kt*5;
            p4h[s] = &srh[kt][am + kf][0];
        }
        float sgn  = (c < 8) ? 1.0f : 2.0f;   // y = sgn*sigma - (sgn-1): sigmoid | tanh
        float soff = (c < 8) ? 0.0f : -1.0f;
        float* pout = out + (size_t)(b * 8 + c7) * 257000 + t0 * 257 + f0 + q * 4;
        for (int u = 2*wave; u < 16; u += 8) {
            int i4 = u >> 1;
            int d0 = i4*768, d1 = d0 + 256;
            f32x4 aA = {bias4, bias4, bias4, bias4};
            f32x4 aB = {bias4, bias4, bias4, bias4};
            #pragma unroll
            for (int s = 0; s < 5; ++s) {
                bf16x8 a0 = *(const bf16x8*)((const char*)p4[s] + d0);
                bf16x8 a1 = *(const bf16x8*)((const char*)p4[s] + d1);
                aA = __builtin_amdgcn_mfma_f32_16x16x32_bf16(a0, fzx[s], aA, 0, 0, 0);
                aB = __builtin_amdgcn_mfma_f32_16x16x32_bf16(a1, fzx[s], aB, 0, 0, 0);
            }
            #pragma unroll
            for (int s = 0; s < 3; ++s) {
                bf16x8 a0 = *(const bf16x8*)((const char*)p4h[s] + d0);
                bf16x8 a1 = *(const bf16x8*)((const char*)p4h[s] + d1);
                aA = __builtin_amdgcn_mfma_f32_16x16x32_bf16(a0, fhn[s], aA, 0, 0, 0);
                aB = __builtin_amdgcn_mfma_f32_16x16x32_bf16(a1, fhn[s], aB, 0, 0, 0);
            }
            float yA0 = fmaf(sig2(aA[0]), sgn, soff);
            float yA1 = fmaf(sig2(aA[1]), sgn, soff);
            float yA2 = fmaf(sig2(aA[2]), sgn, soff);
            float yA3 = fmaf(sig2(aA[3]), sgn, soff);
            float yB0 = fmaf(sig2(aB[0]), sgn, soff);
            float yB1 = fmaf(sig2(aB[1]), sgn, soff);
            float yB2 = fmaf(sig2(aB[2]), sgn, soff);
            float yB3 = fmaf(sig2(aB[3]), sgn, soff);
            float nA0 = __shfl_xor(yA0, 8);   // swap z <-> n
            float nA1 = __shfl_xor(yA1, 8);
            float nA2 = __shfl_xor(yA2, 8);
            float nA3 = __shfl_xor(yA3, 8);
            float nB0 = __shfl_xor(yB0, 8);
            float nB1 = __shfl_xor(yB1, 8);
            float nB2 = __shfl_xor(yB2, 8);
            float nB3 = __shfl_xor(yB3, 8);
            if (c < 8) {
                const unsigned short* phA = &sh[i4 + 2][4 + q*4][c];
                const unsigned short* phB = phA + 128;   // +16 cols
                float hA0 = bf2f(phA[0]),  hA1 = bf2f(phA[8]);
                float hA2 = bf2f(phA[16]), hA3 = bf2f(phA[24]);
                float hB0 = bf2f(phB[0]),  hB1 = bf2f(phB[8]);
                float hB2 = bf2f(phB[16]), hB3 = bf2f(phB[24]);
                float oA0 = fmaf(yA0, nA0 - hA0, hA0);   // (1-z)h + z n
                float oA1 = fmaf(yA1, nA1 - hA1, hA1);
                float oA2 = fmaf(yA2, nA2 - hA2, hA2);
                float oA3 = fmaf(yA3, nA3 - hA3, hA3);
                float oB0 = fmaf(yB0, nB0 - hB0, hB0);
                float oB1 = fmaf(yB1, nB1 - hB1, hB1);
                float oB2 = fmaf(yB2, nB2 - hB2, hB2);
                float oB3 = fmaf(yB3, nB3 - hB3, hB3);
                float* ppA = pout + i4*257;
                float* ppB = ppA + 16;
                int g0A = f0 + q*4;
                int g0B = g0A + 16;
                if (g0A + 3 < 257) {
                    ppA[0] = oA0; ppA[1] = oA1; ppA[2] = oA2; ppA[3] = oA3;
                } else {
                    if (g0A     < 257) ppA[0] = oA0;
                    if (g0A + 1 < 257) ppA[1] = oA1;
                    if (g0A + 2 < 257) ppA[2] = oA2;
                    if (g0A + 3 < 257) ppA[3] = oA3;
                }
                if (g0B + 3 < 257) {
                    ppB[0] = oB0; ppB[1] = oB1; ppB[2] = oB2; ppB[3] = oB3;
                } else {
                    if (g0B     < 257) ppB[0] = oB0;
                    if (g0B + 1 < 257) ppB[1] = oB1;
                    if (g0B + 2 < 257) ppB[2] = oB2;
                    if (g0B + 3 < 257) ppB[3] = oB3;
                }
            }
        }
    }
}

extern "C" void kernel_launch(void* const* d_in, const int* in_sizes, int n_in,
                              void* d_out, int out_size, void* d_ws, size_t ws_size,
                              hipStream_t stream) {
    const float* x     = (const float*)d_in[0];
    const float* h     = (const float*)d_in[1];
    const float* pre_w = (const float*)d_in[2];
    const float* pre_b = (const float*)d_in[3];
    const float* xz_w  = (const float*)d_in[4];
    const float* xz_b  = (const float*)d_in[5];
    const float* xr_w  = (const float*)d_in[6];
    const float* xr_b  = (const float*)d_in[7];
    const float* xn_w  = (const float*)d_in[8];
    const float* xn_b  = (const float*)d_in[9];
    const float* hz_w  = (const float*)d_in[10];
    const float* hz_b  = (const float*)d_in[11];
    const float* hr_w  = (const float*)d_in[12];
    const float* hr_b  = (const float*)d_in[13];
    const float* hn_w  = (const float*)d_in[14];
    const float* hn_b  = (const float*)d_in[15];
    float* out = (float*)d_out;

    dim3 grid(9, 125, 16);   // ceil(257/32) x 1000/8 x B
    dim3 block(256);
    gru_mfma<<<grid, block, 0, stream>>>(x, h,
        pre_w, pre_b, xz_w, xz_b, xr_w, xr_b, xn_w, xn_b,
        hz_w, hz_b, hr_w, hr_b, hn_w, hn_b, out);
}

// Round 7
// 413.362 us; speedup vs baseline: 1.3447x; 1.1062x over previous
//
#include <hip/hip_runtime.h>

#define T_ 1000
#define F_ 257
#define L2E 1.4426950408889634f

typedef short bf16x8 __attribute__((ext_vector_type(8)));
typedef short bf16x4 __attribute__((ext_vector_type(4)));
typedef float f32x4  __attribute__((ext_vector_type(4)));

__device__ __forceinline__ unsigned short f2bf(float f) {
    unsigned int u = __float_as_uint(f);
    u += 0x7fffu + ((u >> 16) & 1u);          // round-to-nearest-even
    return (unsigned short)(u >> 16);
}
__device__ __forceinline__ float bf2f(unsigned short h) {
    return __uint_as_float(((unsigned int)h) << 16);
}
// 2 fp32 -> packed 2x bf16 (RNE) in one instruction
__device__ __forceinline__ unsigned cvt_pk_bf16(float a, float b) {
    unsigned r;
    asm("v_cvt_pk_bf16_f32 %0, %1, %2" : "=v"(r) : "v"(a), "v"(b));
    return r;
}
// 1/(1+2^-a) : sigmoid of the log2e-prescaled logit
__device__ __forceinline__ float sig2(float a) {
    return __builtin_amdgcn_rcpf(1.0f + __builtin_amdgcn_exp2f(-a));
}

// T-tile = 20 rows (grid.y = 50), 512 threads (8 waves), 2 blocks/CU (LDS ~71.7KB).
extern "C" __global__ __launch_bounds__(512, 4)
void gru_mfma(const float* __restrict__ x, const float* __restrict__ h,
              const float* __restrict__ pre_w, const float* __restrict__ pre_b,
              const float* __restrict__ xz_w, const float* __restrict__ xz_b,
              const float* __restrict__ xr_w, const float* __restrict__ xr_b,
              const float* __restrict__ xn_w, const float* __restrict__ xn_b,
              const float* __restrict__ hz_w, const float* __restrict__ hz_b,
              const float* __restrict__ hr_w, const float* __restrict__ hr_b,
              const float* __restrict__ hn_w, const float* __restrict__ hn_b,
              float* __restrict__ out)
{
    // B^T weight tables [n][k] (bf16), z/r rows pre-scaled by log2e, n rows by 2*log2e.
    __shared__ __align__(16) unsigned short BZX[16][160]; // n<8: xz|hz ; n>=8: xn|0
    __shared__ __align__(16) unsigned short BR [ 8][160]; // xr|hr (cols 8-15 duplicate 0-7)
    __shared__ __align__(16) unsigned short BHN[ 8][ 96]; // hn taps<10 (zero-masked in regs for c<8)
    __shared__ __align__(16) unsigned short BPR[ 8][ 64]; // pre (k=tap*4+ci, taps<10)
    // channel-last bf16 activation tiles, strides linear in u:
    // sx row=384B (disp=u*128), sh/sxp/srh row=768B (disp=u*256).
    // Extra rows give wrap-slack; wrap/junk reads feed provably-unused outputs only.
    __shared__ __align__(16) unsigned short sx [24][48][4];  // rows 0..22 staged (cols 0..43)
    __shared__ __align__(16) unsigned short sh [23][48][8];  // rows 0..21 staged (cols 0..39)
    __shared__ __align__(16) unsigned short sxp[23][48][8];
    __shared__ __align__(16) unsigned short srh[22][48][8];

    const int tid  = threadIdx.x;
    const int lane = tid & 63;
    const int wave = tid >> 6;   // 0..7
    const int am   = lane & 15;  // A-fragment row (pixel within 16-seg)
    const int q    = lane >> 4;  // quad
    const int c    = am;         // C/D column (output channel) in epilogues
    const int c7   = c & 7;
    const bool hiB = (c >= 8);   // lane-split: c<8 handles element A, c>=8 element B
    const int f0   = blockIdx.x * 32;
    const int t0   = blockIdx.y * 20;
    const int b    = blockIdx.z;

    // ---- zero only table regions not fully overwritten by the fill ----
    {
        uint4 z4 = {0u, 0u, 0u, 0u};
        if (tid < 320) ((uint4*)BZX)[tid] = z4;
        if (tid < 96) ((uint4*)BHN)[tid] = z4;
        if (tid < 64) ((uint4*)BPR)[tid] = z4;
    }
    __syncthreads();

    // ---- fill weight tables (global OIHW -> [n][k]), activation scales folded in ----
    for (int i = tid; i < 640; i += 512) {
        int co  = i / 80;
        int rem = i - co * 80;
        int ci  = rem / 10;
        int tf  = rem - ci * 10;           // kt*5+kf
        int k   = tf * 8 + ci;
        BZX[co][k]      = f2bf(xz_w[i] * L2E);
        BZX[8+co][k]    = f2bf(xn_w[i] * (2.0f * L2E));
        BZX[co][80+k]   = f2bf(hz_w[i] * L2E);
        BR [co][k]      = f2bf(xr_w[i] * L2E);
        BR [co][80+k]   = f2bf(hr_w[i] * L2E);
        BHN[co][k]      = f2bf(hn_w[i] * (2.0f * L2E));
    }
    for (int i = tid; i < 320; i += 512) {
        int co  = i / 40;
        int rem = i - co * 40;
        int ci  = rem / 10;
        int tf  = rem - ci * 10;
        BPR[co][tf*4 + ci] = f2bf(pre_w[i]);   // elu input: unscaled
    }

    // ---- stage x (rows gt=t0-3+r for r=0..22, cols gf=f0-6+col, zero OOR) ----
    for (int i = tid; i < 23*44; i += 512) {
        int r = i / 44, col = i - r*44;
        int gt = t0 - 3 + r, gf = f0 - 6 + col;
        uint2 pk = {0u, 0u};
        if (gt >= 0 && (unsigned)gf < 257u) {
            const float* p = x + ((size_t)(b * 4) * T_ + gt) * F_ + gf;
            pk.x = cvt_pk_bf16(p[0],        p[257000]);
            pk.y = cvt_pk_bf16(p[2*257000], p[3*257000]);
        }
        *(uint2*)&sx[r][col][0] = pk;
    }
    // ---- stage h (rows gt=t0-2+r for r=0..21, cols gf=f0-4+col) ----
    for (int i = tid; i < 22*40; i += 512) {
        int r = i / 40, col = i - r*40;
        int gt = t0 - 2 + r, gf = f0 - 4 + col;
        uint4 pk = {0u, 0u, 0u, 0u};
        if (gt >= 0 && (unsigned)gf < 257u) {
            const float* p = h + ((size_t)(b * 8) * T_ + gt) * F_ + gf;
            pk.x = cvt_pk_bf16(p[0],        p[257000]);
            pk.y = cvt_pk_bf16(p[2*257000], p[3*257000]);
            pk.z = cvt_pk_bf16(p[4*257000], p[5*257000]);
            pk.w = cvt_pk_bf16(p[6*257000], p[7*257000]);
        }
        *(uint4*)&sh[r][col][0] = pk;
    }

    // ---- per-lane accumulator biases (col = channel), pre-scaled ----
    float bias2 = pre_b[c7];
    float bias3 = (xr_b[c7] + hr_b[c7]) * L2E;
    float bias4 = (c < 8) ? (xz_b[c] + hz_b[c]) * L2E
                          : (xn_b[c7] + hn_b[c7]) * (2.0f * L2E);
    __syncthreads();

    // ================= phase 2: xp = elu(pre-conv(x)), 22 x 48 region =================
    // pair-unrolled (u, u+1); lane-split epilogue (c<8 -> A, c>=8 -> B, dup columns)
    {
        bf16x8 fpre[2];
        const unsigned short* pA[2][2];
        #pragma unroll
        for (int s = 0; s < 2; ++s) {
            fpre[s] = *(const bf16x8*)&BPR[c7][s*32 + q*8];
            int ta = 8*s + 2*q, tb = ta + 1;
            int t1 = (ta < 10) ? ta : 0;      // padded taps -> tap 0 (weights are 0)
            int t2 = (tb < 10) ? tb : 0;
            int kt1 = (t1 >= 5), kf1 = t1 - kt1*5;
            int kt2 = (t2 >= 5), kf2 = t2 - kt2*5;
            pA[s][0] = &sx[kt1][am + kf1][0];
            pA[s][1] = &sx[kt2][am + kf2][0];
        }
        unsigned short* psxp = &sxp[0][q*4][c7];
        for (int u = 2*wave; u < 66; u += 16) {
            int d0 = u << 7, d1 = d0 + 128;   // sx disp = u*128 B
            f32x4 aA = {bias2, bias2, bias2, bias2};
            f32x4 aB = {bias2, bias2, bias2, bias2};
            #pragma unroll
            for (int s = 0; s < 2; ++s) {
                union { bf16x8 v; bf16x4 hh[2]; } a0, a1;
                a0.hh[0] = *(const bf16x4*)((const char*)pA[s][0] + d0);
                a0.hh[1] = *(const bf16x4*)((const char*)pA[s][1] + d0);
                a1.hh[0] = *(const bf16x4*)((const char*)pA[s][0] + d1);
                a1.hh[1] = *(const bf16x4*)((const char*)pA[s][1] + d1);
                aA = __builtin_amdgcn_mfma_f32_16x16x32_bf16(a0.v, fpre[s], aA, 0, 0, 0);
                aB = __builtin_amdgcn_mfma_f32_16x16x32_bf16(a1.v, fpre[s], aB, 0, 0, 0);
            }
            int r2A = u / 3;
            int fsA = u - r2A*3;
            int wrap = (fsA == 2);
            int r2X = hiB ? (r2A + wrap)            : r2A;
            int fsX = hiB ? (wrap ? 0 : fsA + 1)    : fsA;
            int gtX = t0 - 2 + r2X;
            int g0X = f0 - 4 + fsX*16 + q*4;
            float w0 = hiB ? aB[0] : aA[0];
            float w1 = hiB ? aB[1] : aA[1];
            float w2 = hiB ? aB[2] : aA[2];
            float w3 = hiB ? aB[3] : aA[3];
            float e0 = __builtin_amdgcn_exp2f(w0 * L2E) - 1.0f;
            float e1 = __builtin_amdgcn_exp2f(w1 * L2E) - 1.0f;
            float e2 = __builtin_amdgcn_exp2f(w2 * L2E) - 1.0f;
            float e3 = __builtin_amdgcn_exp2f(w3 * L2E) - 1.0f;
            w0 = (w0 > 0.0f) ? w0 : e0;
            w1 = (w1 > 0.0f) ? w1 : e1;
            w2 = (w2 > 0.0f) ? w2 : e2;
            w3 = (w3 > 0.0f) ? w3 : e3;
            bool rowok = (gtX >= 0);
            w0 = (rowok && ((unsigned)(g0X + 0) < 257u)) ? w0 : 0.0f;
            w1 = (rowok && ((unsigned)(g0X + 1) < 257u)) ? w1 : 0.0f;
            w2 = (rowok && ((unsigned)(g0X + 2) < 257u)) ? w2 : 0.0f;
            w3 = (rowok && ((unsigned)(g0X + 3) < 257u)) ? w3 : 0.0f;
            unsigned pk01 = cvt_pk_bf16(w0, w1);
            unsigned pk23 = cvt_pk_bf16(w2, w3);
            unsigned short* ps = psxp + (u << 7) + (hiB ? 128 : 0);  // sxp disp = u*128 shorts
            ps[0]  = (unsigned short)pk01;
            ps[8]  = (unsigned short)(pk01 >> 16);
            ps[16] = (unsigned short)pk23;
            ps[24] = (unsigned short)(pk23 >> 16);
        }
    }
    __syncthreads();

    // ================= phase 3: rh = sigmoid(r-conv) * h, 21 x 48 region =================
    // pair-unrolled; lane-split epilogue (BR cols 8-15 duplicate 0-7)
    {
        bf16x8 fr[5];
        const unsigned short* p3[5];
        #pragma unroll
        for (int s = 0; s < 5; ++s) {
            fr[s] = *(const bf16x8*)&BR[c7][s*32 + q*8];
            int tap = s*4 + q;
            if (tap < 10) {
                int kt = (tap >= 5), kf = tap - kt*5;
                p3[s] = &sxp[kt][am + kf][0];
            } else {
                int tt = tap - 10;
                int kt = (tt >= 5), kf = tt - kt*5;
                p3[s] = &sh[kt][am + kf][0];
            }
        }
        const unsigned short* ph3 = &sh[1][2 + q*4][c7];
        unsigned short*       ps3 = &srh[0][q*4][c7];
        for (int u = 2*wave; u < 63; u += 16) {
            int d0 = u << 8, d1 = d0 + 256;   // disp = u*256 B
            f32x4 aA = {bias3, bias3, bias3, bias3};
            f32x4 aB = {bias3, bias3, bias3, bias3};
            #pragma unroll
            for (int s = 0; s < 5; ++s) {
                bf16x8 a0 = *(const bf16x8*)((const char*)p3[s] + d0);
                bf16x8 a1 = *(const bf16x8*)((const char*)p3[s] + d1);
                aA = __builtin_amdgcn_mfma_f32_16x16x32_bf16(a0, fr[s], aA, 0, 0, 0);
                aB = __builtin_amdgcn_mfma_f32_16x16x32_bf16(a1, fr[s], aB, 0, 0, 0);
            }
            int off = (u << 7) + (hiB ? 128 : 0);   // u*128 shorts (+1 element for B)
            const unsigned short* ph = ph3 + off;
            unsigned short*       ps = ps3 + off;
            float s0 = hiB ? aB[0] : aA[0];
            float s1 = hiB ? aB[1] : aA[1];
            float s2 = hiB ? aB[2] : aA[2];
            float s3 = hiB ? aB[3] : aA[3];
            float v0 = sig2(s0) * bf2f(ph[0]);
            float v1 = sig2(s1) * bf2f(ph[8]);
            float v2 = sig2(s2) * bf2f(ph[16]);
            float v3 = sig2(s3) * bf2f(ph[24]);
            unsigned pk01 = cvt_pk_bf16(v0, v1);
            unsigned pk23 = cvt_pk_bf16(v2, v3);
            if (!hiB || (u + 1 < 63)) {
                ps[0]  = (unsigned short)pk01;
                ps[8]  = (unsigned short)(pk01 >> 16);
                ps[16] = (unsigned short)pk23;
                ps[24] = (unsigned short)(pk23 >> 16);
            }
        }
    }
    __syncthreads();

    // ================= phase 4: z | n, center 20 x 32, write out =================
    // pair-unrolled: pair = (i4, fs=0) and (i4, fs=1)
    {
        bf16x8 fzx[5], fhn[3];
        const unsigned short* p4[5];
        const unsigned short* p4h[3];
        #pragma unroll
        for (int s = 0; s < 5; ++s) {
            fzx[s] = *(const bf16x8*)&BZX[c][s*32 + q*8];
            int tap = s*4 + q;
            if (tap < 10) {
                int kt = (tap >= 5), kf = tap - kt*5;
                p4[s] = &sxp[1 + kt][2 + am + kf][0];
            } else {
                int tt = tap - 10;
                int kt = (tt >= 5), kf = tt - kt*5;
                p4[s] = &sh[1 + kt][2 + am + kf][0];
            }
        }
        bf16x8 zz = {0, 0, 0, 0, 0, 0, 0, 0};
        #pragma unroll
        for (int s = 0; s < 3; ++s) {
            bf16x8 w = *(const bf16x8*)&BHN[c7][s*32 + q*8];
            fhn[s] = (c >= 8) ? w : zz;       // z-columns must not see srh contributions
            int tap = s*4 + q;
            int tt = (tap < 10) ? tap : 0;    // taps 10,11 have zero weights
            int kt = (tt >= 5), kf = tt - kt*5;
            p4h[s] = &srh[kt][am + kf][0];
        }
        float sgn  = (c < 8) ? 1.0f : 2.0f;   // y = sgn*sigma - (sgn-1): sigmoid | tanh
        float soff = (c < 8) ? 0.0f : -1.0f;
        float* pout = out + (size_t)(b * 8 + c7) * 257000 + t0 * 257 + f0 + q * 4;
        for (int u = 2*wave; u < 40; u += 16) {
            int i4 = u >> 1;
            int d0 = i4*768, d1 = d0 + 256;
            f32x4 aA = {bias4, bias4, bias4, bias4};
            f32x4 aB = {bias4, bias4, bias4, bias4};
            #pragma unroll
            for (int s = 0; s < 5; ++s) {
                bf16x8 a0 = *(const bf16x8*)((const char*)p4[s] + d0);
                bf16x8 a1 = *(const bf16x8*)((const char*)p4[s] + d1);
                aA = __builtin_amdgcn_mfma_f32_16x16x32_bf16(a0, fzx[s], aA, 0, 0, 0);
                aB = __builtin_amdgcn_mfma_f32_16x16x32_bf16(a1, fzx[s], aB, 0, 0, 0);
            }
            #pragma unroll
            for (int s = 0; s < 3; ++s) {
                bf16x8 a0 = *(const bf16x8*)((const char*)p4h[s] + d0);
                bf16x8 a1 = *(const bf16x8*)((const char*)p4h[s] + d1);
                aA = __builtin_amdgcn_mfma_f32_16x16x32_bf16(a0, fhn[s], aA, 0, 0, 0);
                aB = __builtin_amdgcn_mfma_f32_16x16x32_bf16(a1, fhn[s], aB, 0, 0, 0);
            }
            float yA0 = fmaf(sig2(aA[0]), sgn, soff);
            float yA1 = fmaf(sig2(aA[1]), sgn, soff);
            float yA2 = fmaf(sig2(aA[2]), sgn, soff);
            float yA3 = fmaf(sig2(aA[3]), sgn, soff);
            float yB0 = fmaf(sig2(aB[0]), sgn, soff);
            float yB1 = fmaf(sig2(aB[1]), sgn, soff);
            float yB2 = fmaf(sig2(aB[2]), sgn, soff);
            float yB3 = fmaf(sig2(aB[3]), sgn, soff);
            float nA0 = __shfl_xor(yA0, 8);   // swap z <-> n
            float nA1 = __shfl_xor(yA1, 8);
            float nA2 = __shfl_xor(yA2, 8);
            float nA3 = __shfl_xor(yA3, 8);
            float nB0 = __shfl_xor(yB0, 8);
            float nB1 = __shfl_xor(yB1, 8);
            float nB2 = __shfl_xor(yB2, 8);
            float nB3 = __shfl_xor(yB3, 8);
            if (c < 8) {
                const unsigned short* phA = &sh[i4 + 2][4 + q*4][c];
                const unsigned short* phB = phA + 128;   // +16 cols
                float hA0 = bf2f(phA[0]),  hA1 = bf2f(phA[8]);
                float hA2 = bf2f(phA[16]), hA3 = bf2f(phA[24]);
                float hB0 = bf2f(phB[0]),  hB1 = bf2f(phB[8]);
                float hB2 = bf2f(phB[16]), hB3 = bf2f(phB[24]);
                float oA0 = fmaf(yA0, nA0 - hA0, hA0);   // (1-z)h + z n
                float oA1 = fmaf(yA1, nA1 - hA1, hA1);
                float oA2 = fmaf(yA2, nA2 - hA2, hA2);
                float oA3 = fmaf(yA3, nA3 - hA3, hA3);
                float oB0 = fmaf(yB0, nB0 - hB0, hB0);
                float oB1 = fmaf(yB1, nB1 - hB1, hB1);
                float oB2 = fmaf(yB2, nB2 - hB2, hB2);
                float oB3 = fmaf(yB3, nB3 - hB3, hB3);
                float* ppA = pout + i4*257;
                float* ppB = ppA + 16;
                int g0A = f0 + q*4;
                int g0B = g0A + 16;
                if (g0A + 3 < 257) {
                    ppA[0] = oA0; ppA[1] = oA1; ppA[2] = oA2; ppA[3] = oA3;
                } else {
                    if (g0A     < 257) ppA[0] = oA0;
                    if (g0A + 1 < 257) ppA[1] = oA1;
                    if (g0A + 2 < 257) ppA[2] = oA2;
                    if (g0A + 3 < 257) ppA[3] = oA3;
                }
                if (g0B + 3 < 257) {
                    ppB[0] = oB0; ppB[1] = oB1; ppB[2] = oB2; ppB[3] = oB3;
                } else {
                    if (g0B     < 257) ppB[0] = oB0;
                    if (g0B + 1 < 257) ppB[1] = oB1;
                    if (g0B + 2 < 257) ppB[2] = oB2;
                    if (g0B + 3 < 257) ppB[3] = oB3;
                }
            }
        }
    }
}

extern "C" void kernel_launch(void* const* d_in, const int* in_sizes, int n_in,
                              void* d_out, int out_size, void* d_ws, size_t ws_size,
                              hipStream_t stream) {
    const float* x     = (const float*)d_in[0];
    const float* h     = (const float*)d_in[1];
    const float* pre_w = (const float*)d_in[2];
    const float* pre_b = (const float*)d_in[3];
    const float* xz_w  = (const float*)d_in[4];
    const float* xz_b  = (const float*)d_in[5];
    const float* xr_w  = (const float*)d_in[6];
    const float* xr_b  = (const float*)d_in[7];
    const float* xn_w  = (const float*)d_in[8];
    const float* xn_b  = (const float*)d_in[9];
    const float* hz_w  = (const float*)d_in[10];
    const float* hz_b  = (const float*)d_in[11];
    const float* hr_w  = (const float*)d_in[12];
    const float* hr_b  = (const float*)d_in[13];
    const float* hn_w  = (const float*)d_in[14];
    const float* hn_b  = (const float*)d_in[15];
    float* out = (float*)d_out;

    dim3 grid(9, 50, 16);   // ceil(257/32) x 1000/20 x B
    dim3 block(512);
    gru_mfma<<<grid, block, 0, stream>>>(x, h,
        pre_w, pre_b, xz_w, xz_b, xr_w, xr_b, xn_w, xn_b,
        hz_w, hz_b, hr_w, hr_b, hn_w, hn_b, out);
}

// Round 10
// 406.522 us; speedup vs baseline: 1.3673x; 1.0168x over previous
//
#include <hip/hip_runtime.h>

#define T_ 1000
#define F_ 257
#define L2E 1.4426950408889634f

typedef short bf16x8 __attribute__((ext_vector_type(8)));
typedef short bf16x4 __attribute__((ext_vector_type(4)));
typedef float f32x4  __attribute__((ext_vector_type(4)));

__device__ __forceinline__ unsigned short f2bf(float f) {
    unsigned int u = __float_as_uint(f);
    u += 0x7fffu + ((u >> 16) & 1u);          // round-to-nearest-even
    return (unsigned short)(u >> 16);
}
__device__ __forceinline__ float bf2f(unsigned short h) {
    return __uint_as_float(((unsigned int)h) << 16);
}
// 2 fp32 -> packed 2x bf16 (RNE) in one instruction
__device__ __forceinline__ unsigned cvt_pk_bf16(float a, float b) {
    unsigned r;
    asm("v_cvt_pk_bf16_f32 %0, %1, %2" : "=v"(r) : "v"(a), "v"(b));
    return r;
}
// 1/(1+2^-a) : sigmoid of the log2e-prescaled logit
__device__ __forceinline__ float sig2(float a) {
    return __builtin_amdgcn_rcpf(1.0f + __builtin_amdgcn_exp2f(-a));
}

// T-tile = 16 rows (grid.y = 63), 512 threads (8 waves).
// LDS 53,248B -> 3 blocks/CU (24 waves/CU) via sx/srh overlay (sx dead after P2).
extern "C" __global__ __launch_bounds__(512, 6)
void gru_mfma(const float* __restrict__ x, const float* __restrict__ h,
              const float* __restrict__ pre_w, const float* __restrict__ pre_b,
              const float* __restrict__ xz_w, const float* __restrict__ xz_b,
              const float* __restrict__ xr_w, const float* __restrict__ xr_b,
              const float* __restrict__ xn_w, const float* __restrict__ xn_b,
              const float* __restrict__ hz_w, const float* __restrict__ hz_b,
              const float* __restrict__ hr_w, const float* __restrict__ hr_b,
              const float* __restrict__ hn_w, const float* __restrict__ hn_b,
              float* __restrict__ out)
{
    // B^T weight tables [n][k] (bf16), z/r rows pre-scaled by log2e, n rows by 2*log2e.
    __shared__ __align__(16) unsigned short BZX[16][160]; // n<8: xz|hz ; n>=8: xn|0
    __shared__ __align__(16) unsigned short BR [ 8][160]; // xr|hr (cols 8-15 duplicate 0-7)
    __shared__ __align__(16) unsigned short BHN[ 8][ 96]; // hn taps<10 (zero-masked in regs for c<8)
    __shared__ __align__(16) unsigned short BPR[ 8][ 64]; // pre (k=tap*4+ci, taps<10)
    // Overlay buffer: sx[20][48][4] (3840 sh, P2 only) aliases srh[18][48][8] (6912 sh, P3/P4).
    __shared__ __align__(16) unsigned short SXSRH[6912];
    // channel-last bf16 activation tiles, strides linear in u:
    // sx row=384B (disp=u*128), sh/sxp/srh row=768B (disp=u*256).
    __shared__ __align__(16) unsigned short sh [19][48][8];  // rows 0..17 staged (cols 0..39)
    __shared__ __align__(16) unsigned short sxp[19][48][8];

    typedef unsigned short (*sx_t)[48][4];
    typedef unsigned short (*srh_t)[48][8];
    sx_t  sx  = (sx_t)SXSRH;   // valid until end of phase 2
    srh_t srh = (srh_t)SXSRH;  // valid from phase 3

    const int tid  = threadIdx.x;
    const int lane = tid & 63;
    const int wave = tid >> 6;   // 0..7
    const int am   = lane & 15;  // A-fragment row (pixel within 16-seg)
    const int q    = lane >> 4;  // quad
    const int c    = am;         // C/D column (output channel) in epilogues
    const int c7   = c & 7;
    const bool hiB = (c >= 8);   // lane-split: c<8 handles element A, c>=8 element B
    const int f0   = blockIdx.x * 32;
    const int t0   = blockIdx.y * 16;
    const int b    = blockIdx.z;

    // ---- zero only table regions not fully overwritten by the fill ----
    {
        uint4 z4 = {0u, 0u, 0u, 0u};
        if (tid < 320) ((uint4*)BZX)[tid] = z4;
        if (tid < 96) ((uint4*)BHN)[tid] = z4;
        if (tid < 64) ((uint4*)BPR)[tid] = z4;
    }
    __syncthreads();

    // ---- fill weight tables (global OIHW -> [n][k]), activation scales folded in ----
    for (int i = tid; i < 640; i += 512) {
        int co  = i / 80;
        int rem = i - co * 80;
        int ci  = rem / 10;
        int tf  = rem - ci * 10;           // kt*5+kf
        int k   = tf * 8 + ci;
        BZX[co][k]      = f2bf(xz_w[i] * L2E);
        BZX[8+co][k]    = f2bf(xn_w[i] * (2.0f * L2E));
        BZX[co][80+k]   = f2bf(hz_w[i] * L2E);
        BR [co][k]      = f2bf(xr_w[i] * L2E);
        BR [co][80+k]   = f2bf(hr_w[i] * L2E);
        BHN[co][k]      = f2bf(hn_w[i] * (2.0f * L2E));
    }
    for (int i = tid; i < 320; i += 512) {
        int co  = i / 40;
        int rem = i - co * 40;
        int ci  = rem / 10;
        int tf  = rem - ci * 10;
        BPR[co][tf*4 + ci] = f2bf(pre_w[i]);   // elu input: unscaled
    }

    // ---- stage x (rows gt=t0-3+r for r=0..18, cols gf=f0-6+col, zero OOR) ----
    for (int i = tid; i < 19*44; i += 512) {
        int r = i / 44, col = i - r*44;
        int gt = t0 - 3 + r, gf = f0 - 6 + col;
        uint2 pk = {0u, 0u};
        if ((unsigned)gt < 1000u && (unsigned)gf < 257u) {
            const float* p = x + ((size_t)(b * 4) * T_ + gt) * F_ + gf;
            pk.x = cvt_pk_bf16(p[0],        p[257000]);
            pk.y = cvt_pk_bf16(p[2*257000], p[3*257000]);
        }
        *(uint2*)&sx[r][col][0] = pk;
    }
    // ---- stage h (rows gt=t0-2+r for r=0..17, cols gf=f0-4+col) ----
    for (int i = tid; i < 18*40; i += 512) {
        int r = i / 40, col = i - r*40;
        int gt = t0 - 2 + r, gf = f0 - 4 + col;
        uint4 pk = {0u, 0u, 0u, 0u};
        if ((unsigned)gt < 1000u && (unsigned)gf < 257u) {
            const float* p = h + ((size_t)(b * 8) * T_ + gt) * F_ + gf;
            pk.x = cvt_pk_bf16(p[0],        p[257000]);
            pk.y = cvt_pk_bf16(p[2*257000], p[3*257000]);
            pk.z = cvt_pk_bf16(p[4*257000], p[5*257000]);
            pk.w = cvt_pk_bf16(p[6*257000], p[7*257000]);
        }
        *(uint4*)&sh[r][col][0] = pk;
    }

    // ---- per-lane accumulator biases (col = channel), pre-scaled ----
    float bias2 = pre_b[c7];
    float bias3 = (xr_b[c7] + hr_b[c7]) * L2E;
    float bias4 = (c < 8) ? (xz_b[c] + hz_b[c]) * L2E
                          : (xn_b[c7] + hn_b[c7]) * (2.0f * L2E);
    __syncthreads();

    // ================= phase 2: xp = elu(pre-conv(x)), 18 x 48 region =================
    // pair-unrolled (u, u+1); lane-split epilogue (c<8 -> A, c>=8 -> B, dup columns)
    {
        bf16x8 fpre[2];
        const unsigned short* pA[2][2];
        #pragma unroll
        for (int s = 0; s < 2; ++s) {
            fpre[s] = *(const bf16x8*)&BPR[c7][s*32 + q*8];
            int ta = 8*s + 2*q, tb = ta + 1;
            int t1 = (ta < 10) ? ta : 0;      // padded taps -> tap 0 (weights are 0)
            int t2 = (tb < 10) ? tb : 0;
            int kt1 = (t1 >= 5), kf1 = t1 - kt1*5;
            int kt2 = (t2 >= 5), kf2 = t2 - kt2*5;
            pA[s][0] = &sx[kt1][am + kf1][0];
            pA[s][1] = &sx[kt2][am + kf2][0];
        }
        unsigned short* psxp = &sxp[0][q*4][c7];
        for (int u = 2*wave; u < 54; u += 16) {
            int d0 = u << 7, d1 = d0 + 128;   // sx disp = u*128 B
            f32x4 aA = {bias2, bias2, bias2, bias2};
            f32x4 aB = {bias2, bias2, bias2, bias2};
            #pragma unroll
            for (int s = 0; s < 2; ++s) {
                union { bf16x8 v; bf16x4 hh[2]; } a0, a1;
                a0.hh[0] = *(const bf16x4*)((const char*)pA[s][0] + d0);
                a0.hh[1] = *(const bf16x4*)((const char*)pA[s][1] + d0);
                a1.hh[0] = *(const bf16x4*)((const char*)pA[s][0] + d1);
                a1.hh[1] = *(const bf16x4*)((const char*)pA[s][1] + d1);
                aA = __builtin_amdgcn_mfma_f32_16x16x32_bf16(a0.v, fpre[s], aA, 0, 0, 0);
                aB = __builtin_amdgcn_mfma_f32_16x16x32_bf16(a1.v, fpre[s], aB, 0, 0, 0);
            }
            int r2A = u / 3;
            int fsA = u - r2A*3;
            int wrap = (fsA == 2);
            int r2X = hiB ? (r2A + wrap)            : r2A;
            int fsX = hiB ? (wrap ? 0 : fsA + 1)    : fsA;
            int gtX = t0 - 2 + r2X;
            int g0X = f0 - 4 + fsX*16 + q*4;
            float w0 = hiB ? aB[0] : aA[0];
            float w1 = hiB ? aB[1] : aA[1];
            float w2 = hiB ? aB[2] : aA[2];
            float w3 = hiB ? aB[3] : aA[3];
            float e0 = __builtin_amdgcn_exp2f(w0 * L2E) - 1.0f;
            float e1 = __builtin_amdgcn_exp2f(w1 * L2E) - 1.0f;
            float e2 = __builtin_amdgcn_exp2f(w2 * L2E) - 1.0f;
            float e3 = __builtin_amdgcn_exp2f(w3 * L2E) - 1.0f;
            w0 = (w0 > 0.0f) ? w0 : e0;
            w1 = (w1 > 0.0f) ? w1 : e1;
            w2 = (w2 > 0.0f) ? w2 : e2;
            w3 = (w3 > 0.0f) ? w3 : e3;
            bool rowok = (gtX >= 0);
            w0 = (rowok && ((unsigned)(g0X + 0) < 257u)) ? w0 : 0.0f;
            w1 = (rowok && ((unsigned)(g0X + 1) < 257u)) ? w1 : 0.0f;
            w2 = (rowok && ((unsigned)(g0X + 2) < 257u)) ? w2 : 0.0f;
            w3 = (rowok && ((unsigned)(g0X + 3) < 257u)) ? w3 : 0.0f;
            unsigned pk01 = cvt_pk_bf16(w0, w1);
            unsigned pk23 = cvt_pk_bf16(w2, w3);
            unsigned short* ps = psxp + (u << 7) + (hiB ? 128 : 0);  // sxp disp = u*128 shorts
            ps[0]  = (unsigned short)pk01;
            ps[8]  = (unsigned short)(pk01 >> 16);
            ps[16] = (unsigned short)pk23;
            ps[24] = (unsigned short)(pk23 >> 16);
        }
    }
    __syncthreads();

    // ================= phase 3: rh = sigmoid(r-conv) * h, 17 x 48 region =================
    // pair-unrolled; lane-split epilogue (BR cols 8-15 duplicate 0-7)
    // NOTE: srh overlays sx (sx dead after the barrier above).
    {
        bf16x8 fr[5];
        const unsigned short* p3[5];
        #pragma unroll
        for (int s = 0; s < 5; ++s) {
            fr[s] = *(const bf16x8*)&BR[c7][s*32 + q*8];
            int tap = s*4 + q;
            if (tap < 10) {
                int kt = (tap >= 5), kf = tap - kt*5;
                p3[s] = &sxp[kt][am + kf][0];
            } else {
                int tt = tap - 10;
                int kt = (tt >= 5), kf = tt - kt*5;
                p3[s] = &sh[kt][am + kf][0];
            }
        }
        const unsigned short* ph3 = &sh[1][2 + q*4][c7];
        unsigned short*       ps3 = &srh[0][q*4][c7];
        for (int u = 2*wave; u < 51; u += 16) {
            int d0 = u << 8, d1 = d0 + 256;   // disp = u*256 B
            f32x4 aA = {bias3, bias3, bias3, bias3};
            f32x4 aB = {bias3, bias3, bias3, bias3};
            #pragma unroll
            for (int s = 0; s < 5; ++s) {
                bf16x8 a0 = *(const bf16x8*)((const char*)p3[s] + d0);
                bf16x8 a1 = *(const bf16x8*)((const char*)p3[s] + d1);
                aA = __builtin_amdgcn_mfma_f32_16x16x32_bf16(a0, fr[s], aA, 0, 0, 0);
                aB = __builtin_amdgcn_mfma_f32_16x16x32_bf16(a1, fr[s], aB, 0, 0, 0);
            }
            int off = (u << 7) + (hiB ? 128 : 0);   // u*128 shorts (+1 element for B)
            const unsigned short* ph = ph3 + off;
            unsigned short*       ps = ps3 + off;
            float s0 = hiB ? aB[0] : aA[0];
            float s1 = hiB ? aB[1] : aA[1];
            float s2 = hiB ? aB[2] : aA[2];
            float s3 = hiB ? aB[3] : aA[3];
            float v0 = sig2(s0) * bf2f(ph[0]);
            float v1 = sig2(s1) * bf2f(ph[8]);
            float v2 = sig2(s2) * bf2f(ph[16]);
            float v3 = sig2(s3) * bf2f(ph[24]);
            unsigned pk01 = cvt_pk_bf16(v0, v1);
            unsigned pk23 = cvt_pk_bf16(v2, v3);
            if (!hiB || (u + 1 < 51)) {
                ps[0]  = (unsigned short)pk01;
                ps[8]  = (unsigned short)(pk01 >> 16);
                ps[16] = (unsigned short)pk23;
                ps[24] = (unsigned short)(pk23 >> 16);
            }
        }
    }
    __syncthreads();

    // ================= phase 4: z | n, center 16 x 32, write out =================
    // pair-unrolled: pair = (i4, fs=0) and (i4, fs=1)
    {
        bf16x8 fzx[5], fhn[3];
        const unsigned short* p4[5];
        const unsigned short* p4h[3];
        #pragma unroll
        for (int s = 0; s < 5; ++s) {
            fzx[s] = *(const bf16x8*)&BZX[c][s*32 + q*8];
            int tap = s*4 + q;
            if (tap < 10) {
                int kt = (tap >= 5), kf = tap - kt*5;
                p4[s] = &sxp[1 + kt][2 + am + kf][0];
            } else {
                int tt = tap - 10;
                int kt = (tt >= 5), kf = tt - kt*5;
                p4[s] = &sh[1 + kt][2 + am + kf][0];
            }
        }
        bf16x8 zz = {0, 0, 0, 0, 0, 0, 0, 0};
        #pragma unroll
        for (int s = 0; s < 3; ++s) {
            bf16x8 w = *(const bf16x8*)&BHN[c7][s*32 + q*8];
            fhn[s] = (c >= 8) ? w : zz;       // z-columns must not see srh contributions
            int tap = s*4 + q;
            int tt = (tap < 10) ? tap : 0;    // taps 10,11 have zero weights
            int kt = (tt >= 5), kf = tt - kt*5;
            p4h[s] = &srh[kt][am + kf][0];
        }
        float sgn  = (c < 8) ? 1.0f : 2.0f;   // y = sgn*sigma - (sgn-1): sigmoid | tanh
        float soff = (c < 8) ? 0.0f : -1.0f;
        float* pout = out + (size_t)(b * 8 + c7) * 257000 + t0 * 257 + f0 + q * 4;
        for (int u = 2*wave; u < 32; u += 16) {
            int i4 = u >> 1;
            int d0 = i4*768, d1 = d0 + 256;
            f32x4 aA = {bias4, bias4, bias4, bias4};
            f32x4 aB = {bias4, bias4, bias4, bias4};
            #pragma unroll
            for (int s = 0; s < 5; ++s) {
                bf16x8 a0 = *(const bf16x8*)((const char*)p4[s] + d0);
                bf16x8 a1 = *(const bf16x8*)((const char*)p4[s] + d1);
                aA = __builtin_amdgcn_mfma_f32_16x16x32_bf16(a0, fzx[s], aA, 0, 0, 0);
                aB = __builtin_amdgcn_mfma_f32_16x16x32_bf16(a1, fzx[s], aB, 0, 0, 0);
            }
            #pragma unroll
            for (int s = 0; s < 3; ++s) {
                bf16x8 a0 = *(const bf16x8*)((const char*)p4h[s] + d0);
                bf16x8 a1 = *(const bf16x8*)((const char*)p4h[s] + d1);
                aA = __builtin_amdgcn_mfma_f32_16x16x32_bf16(a0, fhn[s], aA, 0, 0, 0);
                aB = __builtin_amdgcn_mfma_f32_16x16x32_bf16(a1, fhn[s], aB, 0, 0, 0);
            }
            float yA0 = fmaf(sig2(aA[0]), sgn, soff);
            float yA1 = fmaf(sig2(aA[1]), sgn, soff);
            float yA2 = fmaf(sig2(aA[2]), sgn, soff);
            float yA3 = fmaf(sig2(aA[3]), sgn, soff);
            float yB0 = fmaf(sig2(aB[0]), sgn, soff);
            float yB1 = fmaf(sig2(aB[1]), sgn, soff);
            float yB2 = fmaf(sig2(aB[2]), sgn, soff);
            float yB3 = fmaf(sig2(aB[3]), sgn, soff);
            float nA0 = __shfl_xor(yA0, 8);   // swap z <-> n
            float nA1 = __shfl_xor(yA1, 8);
            float nA2 = __shfl_xor(yA2, 8);
            float nA3 = __shfl_xor(yA3, 8);
            float nB0 = __shfl_xor(yB0, 8);
            float nB1 = __shfl_xor(yB1, 8);
            float nB2 = __shfl_xor(yB2, 8);
            float nB3 = __shfl_xor(yB3, 8);
            bool trow = (t0 + i4) < 1000;     // last t-block partial (63*16=1008)
            if ((c < 8) && trow) {
                const unsigned short* phA = &sh[i4 + 2][4 + q*4][c];
                const unsigned short* phB = phA + 128;   // +16 cols
                float hA0 = bf2f(phA[0]),  hA1 = bf2f(phA[8]);
                float hA2 = bf2f(phA[16]), hA3 = bf2f(phA[24]);
                float hB0 = bf2f(phB[0]),  hB1 = bf2f(phB[8]);
                float hB2 = bf2f(phB[16]), hB3 = bf2f(phB[24]);
                float oA0 = fmaf(yA0, nA0 - hA0, hA0);   // (1-z)h + z n
                float oA1 = fmaf(yA1, nA1 - hA1, hA1);
                float oA2 = fmaf(yA2, nA2 - hA2, hA2);
                float oA3 = fmaf(yA3, nA3 - hA3, hA3);
                float oB0 = fmaf(yB0, nB0 - hB0, hB0);
                float oB1 = fmaf(yB1, nB1 - hB1, hB1);
                float oB2 = fmaf(yB2, nB2 - hB2, hB2);
                float oB3 = fmaf(yB3, nB3 - hB3, hB3);
                float* ppA = pout + i4*257;
                float* ppB = ppA + 16;
                int g0A = f0 + q*4;
                int g0B = g0A + 16;
                if (g0A + 3 < 257) {
                    ppA[0] = oA0; ppA[1] = oA1; ppA[2] = oA2; ppA[3] = oA3;
                } else {
                    if (g0A     < 257) ppA[0] = oA0;
                    if (g0A + 1 < 257) ppA[1] = oA1;
                    if (g0A + 2 < 257) ppA[2] = oA2;
                    if (g0A + 3 < 257) ppA[3] = oA3;
                }
                if (g0B + 3 < 257) {
                    ppB[0] = oB0; ppB[1] = oB1; ppB[2] = oB2; ppB[3] = oB3;
                } else {
                    if (g0B     < 257) ppB[0] = oB0;
                    if (g0B + 1 < 257) ppB[1] = oB1;
                    if (g0B + 2 < 257) ppB[2] = oB2;
                    if (g0B + 3 < 257) ppB[3] = oB3;
                }
            }
        }
    }
}

extern "C" void kernel_launch(void* const* d_in, const int* in_sizes, int n_in,
                              void* d_out, int out_size, void* d_ws, size_t ws_size,
                              hipStream_t stream) {
    const float* x     = (const float*)d_in[0];
    const float* h     = (const float*)d_in[1];
    const float* pre_w = (const float*)d_in[2];
    const float* pre_b = (const float*)d_in[3];
    const float* xz_w  = (const float*)d_in[4];
    const float* xz_b  = (const float*)d_in[5];
    const float* xr_w  = (const float*)d_in[6];
    const float* xr_b  = (const float*)d_in[7];
    const float* xn_w  = (const float*)d_in[8];
    const float* xn_b  = (const float*)d_in[9];
    const float* hz_w  = (const float*)d_in[10];
    const float* hz_b  = (const float*)d_in[11];
    const float* hr_w  = (const float*)d_in[12];
    const float* hr_b  = (const float*)d_in[13];
    const float* hn_w  = (const float*)d_in[14];
    const float* hn_b  = (const float*)d_in[15];
    float* out = (float*)d_out;

    dim3 grid(9, 63, 16);   // ceil(257/32) x ceil(1000/16) x B
    dim3 block(512);
    gru_mfma<<<grid, block, 0, stream>>>(x, h,
        pre_w, pre_b, xz_w, xz_b, xr_w, xr_b, xn_w, xn_b,
        hz_w, hz_b, hr_w, hr_b, hn_w, hn_b, out);
}